// Round 1
// baseline (217.518 us; speedup 1.0000x reference)
//
#include <hip/hip_runtime.h>
#include <stdint.h>

#define NTYPES 12
#define EMB 128
#define KNN 30
#define SEPS_F 1e-6f
#define LEPS_F 1e6f
#define NATOMS 4800
#define ITEMS 75   // NATOMS / 64

// ---------------- stats1: per-batch per-type mask counts ----------------
__global__ void stats1_kernel(const float* __restrict__ mask, float* __restrict__ cnt_t,
                              float* __restrict__ cnt_all, int N) {
    __shared__ float lc[NTYPES + 1];
    int b = blockIdx.x;
    if (threadIdx.x < NTYPES + 1) lc[threadIdx.x] = 0.f;
    __syncthreads();
    for (int n = threadIdx.x; n < N; n += blockDim.x) {
        float m = mask[b * N + n];
        atomicAdd(&lc[n % NTYPES], m);
        atomicAdd(&lc[NTYPES], m);
    }
    __syncthreads();
    if (threadIdx.x < NTYPES) cnt_t[b * NTYPES + threadIdx.x] = lc[threadIdx.x];
    if (threadIdx.x == NTYPES) cnt_all[b] = lc[NTYPES];
}

// ---------------- stats2: per (b,d) affine coefficients for graph norm ----------------
__global__ void stats2_kernel(const float* __restrict__ w, const float* __restrict__ scale,
                              const float* __restrict__ shift, const float* __restrict__ cnt_t,
                              const float* __restrict__ cnt_all, float* __restrict__ Aa,
                              float* __restrict__ Bb, int B, int N) {
    int tid = blockIdx.x * blockDim.x + threadIdx.x;
    if (tid >= B * EMB) return;
    int b = tid / EMB, d = tid % EMB;
    float cnt = cnt_all[b];
    float c = (cnt == 0.f) ? 1.f : cnt;
    float mean = 0.f;
    for (int t = 0; t < NTYPES; ++t) mean += w[t * EMB + d] * cnt_t[b * NTYPES + t];
    mean /= c;
    float S = 0.f;
    for (int t = 0; t < NTYPES; ++t) {
        float dv = w[t * EMB + d] - mean;
        S += cnt_t[b * NTYPES + t] * dv * dv;
    }
    S += ((float)N - cnt) * mean * mean;   // masked rows contribute mean^2
    float var = S / c;
    float stdv = sqrtf(var + SEPS_F);
    float g = scale[d] / stdv;
    Aa[tid] = g;
    Bb[tid] = shift[d] - mean * g;
}

// ---------------- embedding write ----------------
__global__ __launch_bounds__(256) void emb_kernel(const float* __restrict__ w,
                                                  const float* __restrict__ mask,
                                                  const float* __restrict__ Aa,
                                                  const float* __restrict__ Bb,
                                                  float* __restrict__ out0, int N) {
    int b = blockIdx.y;
    int idx = blockIdx.x * blockDim.x + threadIdx.x;   // [0, N*EMB)
    int d = idx & (EMB - 1);
    int n = idx >> 7;
    float m = mask[b * N + n];
    float x = w[(n % NTYPES) * EMB + d] * m;
    float val = (x * Aa[b * EMB + d] + Bb[b * EMB + d]) * m;
    out0[(size_t)b * N * EMB + idx] = val;
}

// ---------------- exact 30-NN: one wave per query row ----------------
__global__ __launch_bounds__(256) void knn_kernel(const float* __restrict__ coords,
                                                  const float* __restrict__ mask,
                                                  float* __restrict__ outd,
                                                  float* __restrict__ outi,
                                                  int B, int N) {
    __shared__ unsigned long long cand[4][128];
    int wave = threadIdx.x >> 6;
    int lane = threadIdx.x & 63;
    int row = blockIdx.x * 4 + wave;
    int total = B * N;
    if (row >= total) row = total - 1;     // duplicate work, deterministic
    int b = row / N;
    int i = row - b * N;

    const float* cb = coords + (size_t)b * N * 3;
    const float* mb = mask + (size_t)b * N;
    float qx = cb[i * 3 + 0], qy = cb[i * 3 + 1], qz = cb[i * 3 + 2];
    float mi = mb[i];

    unsigned bits[ITEMS];
#pragma unroll
    for (int k = 0; k < ITEMS; ++k) {
        int j = k * 64 + lane;
        float x = cb[j * 3 + 0], y = cb[j * 3 + 1], z = cb[j * 3 + 2];
        float dx = __fsub_rn(x, qx), dy = __fsub_rn(y, qy), dz = __fsub_rn(z, qz);
        float d2 = __fadd_rn(__fadd_rn(__fmul_rn(dx, dx), __fmul_rn(dy, dy)),
                             __fmul_rn(dz, dz));
        float dist = __fsqrt_rn(__fadd_rn(d2, SEPS_F));
        float mj = mb[j];
        if (j == i || mj == 0.f || mi == 0.f) dist = LEPS_F;  // matches ref exactly (f32)
        bits[k] = __float_as_uint(dist);
    }

    // wave-wide min of bits
    unsigned mn = bits[0];
#pragma unroll
    for (int k = 1; k < ITEMS; ++k) mn = (bits[k] < mn) ? bits[k] : mn;
    for (int s = 32; s >= 1; s >>= 1) {
        unsigned o = (unsigned)__shfl_xor((int)mn, s, 64);
        mn = (o < mn) ? o : mn;
    }

    // count of items with bits <= T, across whole wave (all 4800 via ballot+popc)
    auto countLe = [&](unsigned T) -> int {
        int c = 0;
#pragma unroll
        for (int k = 0; k < ITEMS; ++k)
            c += __popcll(__ballot(bits[k] <= T));
        return c;
    };

    const unsigned CAP = 0x49742400u;  // bit pattern of 1e6f; count(CAP) == N >= 30 always
    unsigned lo = mn, hi = CAP;
    // smallest T in [mn, CAP] with countLe(T) >= KNN
    while (lo < hi) {
        unsigned mid = lo + ((hi - lo) >> 1);
        if (countLe(mid) >= KNN) hi = mid; else lo = mid + 1;
    }
    unsigned T30 = lo;

    // compact candidates (ascending j order) into LDS
    unsigned long long* cw = cand[wave];
    int Mtot = 0;
#pragma unroll
    for (int k = 0; k < ITEMS; ++k) {
        bool p = (bits[k] <= T30);
        unsigned long long bal = __ballot(p);
        if (p) {
            int pos = Mtot + __popcll(bal & ((1ull << lane) - 1ull));
            if (pos < 128)
                cw[pos] = ((unsigned long long)bits[k] << 32) | (unsigned)(k * 64 + lane);
        }
        Mtot += __popcll(bal);
    }
    if (Mtot > 128) Mtot = 128;

    __syncthreads();   // make LDS writes visible (also safe across the 4 waves)

    // exact rank of each candidate by all-pairs compare on (bits, idx) key
    for (int cidx = lane; cidx < Mtot; cidx += 64) {
        unsigned long long key = cw[cidx];
        int rank = 0;
        for (int o = 0; o < Mtot; ++o) rank += (cw[o] < key) ? 1 : 0;
        if (rank < KNN) {
            float dval = __uint_as_float((unsigned)(key >> 32));
            int j = (int)(key & 0xffffffffu);
            float iv = (float)j;
            if (j == i) iv = -1.f;
            if (mi == 0.f) { iv = -1.f; dval = LEPS_F; }
            size_t o0 = (size_t)row * KNN + rank;
            outd[o0] = dval;
            outi[o0] = iv;
        }
    }
}

extern "C" void kernel_launch(void* const* d_in, const int* in_sizes, int n_in,
                              void* d_out, int out_size, void* d_ws, size_t ws_size,
                              hipStream_t stream) {
    const float* coords = (const float*)d_in[0];
    const float* mask   = (const float*)d_in[1];
    const float* w      = (const float*)d_in[2];
    const float* scale  = (const float*)d_in[3];
    const float* shift  = (const float*)d_in[4];

    int BN = in_sizes[1];          // B*N
    int N  = NATOMS;
    int B  = BN / N;

    float* ws      = (float*)d_ws;
    float* cnt_t   = ws;                        // B*12
    float* cnt_all = ws + B * NTYPES;           // B
    float* Aa      = cnt_all + B;               // B*128
    float* Bb      = Aa + B * EMB;              // B*128

    float* out0 = (float*)d_out;                      // B*N*128
    float* outd = out0 + (size_t)B * N * EMB;         // B*N*30
    float* outi = outd + (size_t)B * N * KNN;         // B*N*30 (indices as float)

    stats1_kernel<<<B, 256, 0, stream>>>(mask, cnt_t, cnt_all, N);
    stats2_kernel<<<(B * EMB + 255) / 256, 256, 0, stream>>>(w, scale, shift, cnt_t,
                                                             cnt_all, Aa, Bb, B, N);
    emb_kernel<<<dim3((N * EMB) / 256, B), 256, 0, stream>>>(w, mask, Aa, Bb, out0, N);
    knn_kernel<<<(B * N + 3) / 4, 256, 0, stream>>>(coords, mask, outd, outi, B, N);
}

// Round 2
// 96.306 us; speedup vs baseline: 2.2586x; 2.2586x over previous
//
#include <hip/hip_runtime.h>
#include <stdint.h>

#define NTYPES 12
#define EMB 128
#define KNN 30
#define SEPS_F 1e-6f
#define LEPS_F 1e6f
#define NATOMS 4800
#define ITEMS 75            // NATOMS / 64
#define CAPC 192            // candidate capacity per wave
#define SENT_BITS 0x7F7FFFFFu   // FLT_MAX bit pattern: sentinel for masked items

typedef unsigned long long ull;

__device__ __forceinline__ ull shfl_xor64(ull v, int m) {
    int lo = (int)(unsigned)(v & 0xffffffffull);
    int hi = (int)(unsigned)(v >> 32);
    lo = __shfl_xor(lo, m, 64);
    hi = __shfl_xor(hi, m, 64);
    return ((ull)(unsigned)hi << 32) | (unsigned)lo;
}

// ---------------- stats1: per-batch per-type mask counts ----------------
__global__ void stats1_kernel(const float* __restrict__ mask, float* __restrict__ cnt_t,
                              float* __restrict__ cnt_all, int N) {
    __shared__ float lc[NTYPES + 1];
    int b = blockIdx.x;
    if (threadIdx.x < NTYPES + 1) lc[threadIdx.x] = 0.f;
    __syncthreads();
    for (int n = threadIdx.x; n < N; n += blockDim.x) {
        float m = mask[b * N + n];
        atomicAdd(&lc[n % NTYPES], m);
        atomicAdd(&lc[NTYPES], m);
    }
    __syncthreads();
    if (threadIdx.x < NTYPES) cnt_t[b * NTYPES + threadIdx.x] = lc[threadIdx.x];
    if (threadIdx.x == NTYPES) cnt_all[b] = lc[NTYPES];
}

// ---------------- stats2: per (b,d) affine coefficients for graph norm ----------------
__global__ void stats2_kernel(const float* __restrict__ w, const float* __restrict__ scale,
                              const float* __restrict__ shift, const float* __restrict__ cnt_t,
                              const float* __restrict__ cnt_all, float* __restrict__ Aa,
                              float* __restrict__ Bb, int B, int N) {
    int tid = blockIdx.x * blockDim.x + threadIdx.x;
    if (tid >= B * EMB) return;
    int b = tid / EMB, d = tid % EMB;
    float cnt = cnt_all[b];
    float c = (cnt == 0.f) ? 1.f : cnt;
    float mean = 0.f;
    for (int t = 0; t < NTYPES; ++t) mean += w[t * EMB + d] * cnt_t[b * NTYPES + t];
    mean /= c;
    float S = 0.f;
    for (int t = 0; t < NTYPES; ++t) {
        float dv = w[t * EMB + d] - mean;
        S += cnt_t[b * NTYPES + t] * dv * dv;
    }
    S += ((float)N - cnt) * mean * mean;
    float var = S / c;
    float stdv = sqrtf(var + SEPS_F);
    float g = scale[d] / stdv;
    Aa[tid] = g;
    Bb[tid] = shift[d] - mean * g;
}

// ---------------- embedding write ----------------
__global__ __launch_bounds__(256) void emb_kernel(const float* __restrict__ w,
                                                  const float* __restrict__ mask,
                                                  const float* __restrict__ Aa,
                                                  const float* __restrict__ Bb,
                                                  float* __restrict__ out0, int N) {
    int b = blockIdx.y;
    int idx = blockIdx.x * blockDim.x + threadIdx.x;
    int d = idx & (EMB - 1);
    int n = idx >> 7;
    float m = mask[b * N + n];
    float x = w[(n % NTYPES) * EMB + d] * m;
    float val = (x * Aa[b * EMB + d] + Bb[b * EMB + d]) * m;
    out0[(size_t)b * N * EMB + idx] = val;
}

// ---------------- exact 30-NN: one wave per query row ----------------
__global__ __launch_bounds__(256) void knn_kernel(const float* __restrict__ coords,
                                                  const float* __restrict__ mask,
                                                  const float* __restrict__ cnt_all,
                                                  float* __restrict__ outd,
                                                  float* __restrict__ outi,
                                                  int B, int N) {
    __shared__ ull cand[4][CAPC];
    const int wave = threadIdx.x >> 6;
    const int lane = threadIdx.x & 63;
    int row = blockIdx.x * 4 + wave;
    const int total = B * N;
    if (row >= total) row = total - 1;   // duplicate work, deterministic
    const int b = row / N;
    const int i = row - b * N;

    const float* cb = coords + (size_t)b * N * 3;
    const float* mb = mask + (size_t)b * N;
    const float qx = cb[i * 3 + 0], qy = cb[i * 3 + 1], qz = cb[i * 3 + 2];
    const float mi = mb[i];

    // masked query row: constant outputs, exit early
    if (mi == 0.f) {
        if (lane < KNN) {
            size_t o0 = (size_t)row * KNN + lane;
            outd[o0] = LEPS_F;
            outi[o0] = -1.f;
        }
        return;
    }

    const bool allOnes = (cnt_all[b] == (float)N);

    // ---- squared distances (bit-exact plain f32 ops, no FMA, no sqrt here) ----
    unsigned bits[ITEMS];
    unsigned lm = 0xFFFFFFFFu;   // per-lane min of d2 bits
    if (allOnes) {
#pragma unroll
        for (int k = 0; k < ITEMS; ++k) {
            int j = k * 64 + lane;
            float x = cb[j * 3 + 0], y = cb[j * 3 + 1], z = cb[j * 3 + 2];
            float dx = __fsub_rn(x, qx), dy = __fsub_rn(y, qy), dz = __fsub_rn(z, qz);
            float d2 = __fadd_rn(__fadd_rn(__fmul_rn(dx, dx), __fmul_rn(dy, dy)),
                                 __fmul_rn(dz, dz));
            unsigned ub = __float_as_uint(d2);
            bits[k] = ub;
            lm = (ub < lm) ? ub : lm;
        }
    } else {
#pragma unroll
        for (int k = 0; k < ITEMS; ++k) {
            int j = k * 64 + lane;
            float x = cb[j * 3 + 0], y = cb[j * 3 + 1], z = cb[j * 3 + 2];
            float dx = __fsub_rn(x, qx), dy = __fsub_rn(y, qy), dz = __fsub_rn(z, qz);
            float d2 = __fadd_rn(__fadd_rn(__fmul_rn(dx, dx), __fmul_rn(dy, dy)),
                                 __fmul_rn(dz, dz));
            unsigned ub = __float_as_uint(d2);
            if (mb[j] == 0.f) ub = SENT_BITS;    // masked item sentinel
            bits[k] = ub;
            lm = (ub < lm) ? ub : lm;
        }
    }

    // ---- threshold estimate: ~35th smallest of the 64 lane-mins ----
    unsigned mx = lm;
    for (int s = 32; s >= 1; s >>= 1) {
        unsigned o = (unsigned)__shfl_xor((int)mx, s, 64);
        mx = (o > mx) ? o : mx;
    }
    unsigned elo = 0, ehi = mx;
    while (elo + 4096u < ehi) {
        unsigned mid = elo + ((ehi - elo) >> 1);
        int cnt = __popcll(__ballot(lm <= mid));
        if (cnt >= 35) ehi = mid; else elo = mid + 1;
    }
    unsigned T = ehi;

    // ---- fused count + compact, with windowed adjust (count in [31, CAPC]) ----
    ull* cw = cand[wave];
    const ull lmaskLT = (1ull << lane) - 1ull;
    int c;
    unsigned blo = 0, bhi = SENT_BITS;
    bool forced = false;
    for (;;) {
        c = 0;
#pragma unroll
        for (int k = 0; k < ITEMS; ++k) {
            bool p = (bits[k] <= T);
            ull bal = __ballot(p);
            if (p) {
                int pos = c + __popcll(bal & lmaskLT);
                if (pos < CAPC)
                    cw[pos] = ((ull)bits[k] << 32) | (unsigned)(k * 64 + lane);
            }
            c += __popcll(bal);
        }
        if (forced || (c >= KNN + 1 && c <= CAPC)) break;
        if (c < KNN + 1) blo = T + 1; else bhi = T - 1;
        if (blo > bhi) { T = blo; forced = true; }   // tie jam: smallest T with count>=31
        else T = blo + ((bhi - blo) >> 1);
    }
    if (c > CAPC) c = CAPC;

    asm volatile("s_waitcnt lgkmcnt(0)" ::: "memory");

    if (c <= 64) {
        // ---- register bitonic sort of 64 keys (dist_bits<<32 | j), ascending ----
        ull key = ~0ull;
        if (lane < c) {
            ull kk = cw[lane];
            unsigned db = (unsigned)(kk >> 32);
            unsigned jj = (unsigned)kk;
            float dist;
            if (db == SENT_BITS || jj == (unsigned)i) dist = LEPS_F;
            else dist = __fsqrt_rn(__fadd_rn(__uint_as_float(db), SEPS_F));
            key = ((ull)__float_as_uint(dist) << 32) | jj;
        }
        for (int kk2 = 2; kk2 <= 64; kk2 <<= 1) {
            for (int jj2 = kk2 >> 1; jj2 > 0; jj2 >>= 1) {
                ull o = shfl_xor64(key, jj2);
                bool up = ((lane & kk2) == 0);
                bool takeMin = (((lane & jj2) == 0) == up);
                ull mn2 = (key < o) ? key : o;
                ull mx2 = (key < o) ? o : key;
                key = takeMin ? mn2 : mx2;
            }
        }
        if (lane < KNN) {
            unsigned db = (unsigned)(key >> 32);
            unsigned jj = (unsigned)key;
            float dv = __uint_as_float(db);
            float iv = (jj == (unsigned)i) ? -1.f : (float)jj;
            size_t o0 = (size_t)row * KNN + lane;
            outd[o0] = dv;
            outi[o0] = iv;
        }
    } else {
        // ---- rare path: transform keys to dist space, all-pairs rank via LDS ----
        for (int ci = lane; ci < c; ci += 64) {
            ull kk = cw[ci];
            unsigned db = (unsigned)(kk >> 32);
            unsigned jj = (unsigned)kk;
            float dist;
            if (db == SENT_BITS || jj == (unsigned)i) dist = LEPS_F;
            else dist = __fsqrt_rn(__fadd_rn(__uint_as_float(db), SEPS_F));
            cw[ci] = ((ull)__float_as_uint(dist) << 32) | jj;
        }
        asm volatile("s_waitcnt lgkmcnt(0)" ::: "memory");
        for (int ci = lane; ci < c; ci += 64) {
            ull key = cw[ci];
            int rank = 0;
            for (int o = 0; o < c; ++o) rank += (cw[o] < key) ? 1 : 0;
            if (rank < KNN) {
                unsigned db = (unsigned)(key >> 32);
                unsigned jj = (unsigned)key;
                float dv = __uint_as_float(db);
                float iv = (jj == (unsigned)i) ? -1.f : (float)jj;
                size_t o0 = (size_t)row * KNN + rank;
                outd[o0] = dv;
                outi[o0] = iv;
            }
        }
    }
}

extern "C" void kernel_launch(void* const* d_in, const int* in_sizes, int n_in,
                              void* d_out, int out_size, void* d_ws, size_t ws_size,
                              hipStream_t stream) {
    const float* coords = (const float*)d_in[0];
    const float* mask   = (const float*)d_in[1];
    const float* w      = (const float*)d_in[2];
    const float* scale  = (const float*)d_in[3];
    const float* shift  = (const float*)d_in[4];

    int BN = in_sizes[1];          // B*N
    int N  = NATOMS;
    int B  = BN / N;

    float* ws      = (float*)d_ws;
    float* cnt_t   = ws;                        // B*12
    float* cnt_all = ws + B * NTYPES;           // B
    float* Aa      = cnt_all + B;               // B*128
    float* Bb      = Aa + B * EMB;              // B*128

    float* out0 = (float*)d_out;                      // B*N*128
    float* outd = out0 + (size_t)B * N * EMB;         // B*N*30
    float* outi = outd + (size_t)B * N * KNN;         // B*N*30 (indices as float)

    stats1_kernel<<<B, 256, 0, stream>>>(mask, cnt_t, cnt_all, N);
    stats2_kernel<<<(B * EMB + 255) / 256, 256, 0, stream>>>(w, scale, shift, cnt_t,
                                                             cnt_all, Aa, Bb, B, N);
    emb_kernel<<<dim3((N * EMB) / 256, B), 256, 0, stream>>>(w, mask, Aa, Bb, out0, N);
    knn_kernel<<<(B * N + 3) / 4, 256, 0, stream>>>(coords, mask, cnt_all, outd, outi, B, N);
}